// Round 10
// baseline (158.583 us; speedup 1.0000x reference)
//
#include <hip/hip_runtime.h>
#include <hip/hip_bf16.h>
#include <math.h>

// CrossEntropy3d OHEM: predict (n=2, c=12, d=64, h=128, w=128) f32,
// target (2,64,128,128) int32. Class stride = d*h*w = 1<<20 floats (4 MB).
//
// R10: async global_load_lds staging. Evidence chain: pass is bound by
// outstanding-fetch depth (R6 latency-scaling, R5/R4 TLP/ILP-neutral,
// register variants cap at <=8KB in flight/wave). global_load_lds queues
// fetches with ZERO VGPR cost: 12 issues/wave (12KB in flight), one
// barrier, then compute from LDS. m97 GEMM sustains ~3.5TB/s staging
// strided tiles through exactly this path. R7 (same tile shape, but
// synchronous 4-load batches) = 132us main is the control.
// Structure/epilogue = R9 (best known, 157.9us total).
// Fixed harness overhead in timed window: ws poison ~59us + d_in restore
// ~33us => ~95us floor.

#define IGNORE_LABEL 255
#define MIN_KEPT 10000u

constexpr int   C         = 12;
constexpr int   PIX_SHIFT = 20;              // d*h*w = 1<<20
constexpr int   PIX_MASK  = (1 << PIX_SHIFT) - 1;
constexpr int   TILE      = 1024;            // pixels per block
constexpr int   NBINS     = 2048;            // histogram over (0.9, 1.0]
constexpr float BIN_SCALE = (float)NBINS / 0.1f;

struct Ws {
    double       sum_p3;     // fallback sum (atomics; rare path only)
    unsigned int cnt_p3;
    unsigned int flag;       // 1 => fallback must run
    float        threshold;  // fallback threshold
    unsigned int done;       // (unused)
    unsigned int done2;      // fallback arrival counter
    unsigned int pad[9];     // pad to 64 B
    unsigned int hist[NBINS];
};
// uint4 per main block (sle, sva as float bits; cle, cva) right after Ws.

__device__ inline float wave_reduce_f(float v) {
    #pragma unroll
    for (int o = 32; o > 0; o >>= 1) v += __shfl_down(v, o, 64);
    return v;
}
__device__ inline unsigned int wave_reduce_u(unsigned int v) {
    #pragma unroll
    for (int o = 32; o > 0; o >>= 1) v += __shfl_down(v, o, 64);
    return v;
}
__device__ inline double wave_reduce_d(double v) {
    #pragma unroll
    for (int o = 32; o > 0; o >>= 1) v += __shfl_down(v, o, 64);
    return v;
}

// async 16B/lane global->LDS: lane i's 16B land at lds_base + i*16.
__device__ inline void gld_lds16(const float* gsrc, float* ldst) {
    __builtin_amdgcn_global_load_lds(
        (const __attribute__((address_space(1))) unsigned int*)gsrc,
        (__attribute__((address_space(3))) unsigned int*)ldst,
        16, 0, 0);
}

__global__ __launch_bounds__(256, 3) void main_pass_kernel(
        const float* __restrict__ pred, const int* __restrict__ tgt,
        Ws* __restrict__ ws, uint4* __restrict__ partials) {
    __shared__ float tileA[C][TILE];          // 48 KB

    const int wid  = threadIdx.x >> 6;        // wave 0..3
    const int lane = threadIdx.x & 63;
    const int tile0 = blockIdx.x * TILE;      // tile never crosses n boundary
    const int ni    = tile0 >> PIX_SHIFT;
    const int rem   = tile0 & PIX_MASK;
    const float* nbase = pred + (((size_t)ni * C) << PIX_SHIFT) + rem;

    // ---- async staging: wave w queues classes 3w..3w+2, 4x 1KB wave-loads
    //      each, 12 global_load_lds back-to-back, ZERO VGPR results, no
    //      intermediate waits. 12KB in flight per wave. ----
    #pragma unroll
    for (int cc = 0; cc < 3; ++cc) {
        const int c = wid * 3 + cc;
        const float* gsrc = nbase + ((size_t)c << PIX_SHIFT);
        #pragma unroll
        for (int k = 0; k < 4; ++k)
            gld_lds16(gsrc + k * 256 + lane * 4, &tileA[c][k * 256]);
    }

    // labels for this thread's 4 pixels (overlaps with DMA drain)
    const int4 li = *(const int4*)(tgt + tile0 + threadIdx.x * 4);
    const int lab[4] = {li.x, li.y, li.z, li.w};

    __syncthreads();                          // drains vmcnt + barrier

    // ---- compute: gather 12 classes per pixel from LDS ----
    float s[4]     = {0.0f, 0.0f, 0.0f, 0.0f};
    float l_lab[4] = {0.0f, 0.0f, 0.0f, 0.0f};
    #pragma unroll
    for (int c = 0; c < C; ++c) {
        const float4 v = *(const float4*)&tileA[c][threadIdx.x * 4];
        const float vv[4] = {v.x, v.y, v.z, v.w};
        #pragma unroll
        for (int j = 0; j < 4; ++j) {
            s[j] += __expf(vv[j]);
            if (lab[j] == c) l_lab[j] = vv[j];
        }
    }

    float        my_sle = 0.0f, my_sva = 0.0f;
    unsigned int my_cle = 0u,   my_cva = 0u;
    #pragma unroll
    for (int j = 0; j < 4; ++j) {
        const float ls   = __logf(s[j]);
        const float nll  = ls - l_lab[j];
        const float prob = __expf(l_lab[j] - ls);
        if (lab[j] != IGNORE_LABEL) {
            my_cva += 1u;
            my_sva += nll;
            if (prob <= 0.9f) {
                my_cle += 1u;
                my_sle += nll;
            } else {
                int b = (int)((prob - 0.9f) * BIN_SCALE);
                b = b < 0 ? 0 : (b >= NBINS - 1 ? NBINS - 1 : b);
                atomicAdd(&ws->hist[b], 1u);   // rare
            }
        }
    }

    // ---- block reduction -> one partial store per block (R9 epilogue) ----
    __shared__ float        s_le[4], s_va[4];
    __shared__ unsigned int s_cle[4], s_cva[4];
    const float        r_le = wave_reduce_f(my_sle);
    const float        r_va = wave_reduce_f(my_sva);
    const unsigned int r_cl = wave_reduce_u(my_cle);
    const unsigned int r_cv = wave_reduce_u(my_cva);
    if (lane == 0) { s_le[wid] = r_le; s_va[wid] = r_va; s_cle[wid] = r_cl; s_cva[wid] = r_cv; }
    __syncthreads();
    if (threadIdx.x == 0) {
        uint4 p;
        p.x = __float_as_uint(s_le[0] + s_le[1] + s_le[2] + s_le[3]);
        p.y = __float_as_uint(s_va[0] + s_va[1] + s_va[2] + s_va[3]);
        p.z = s_cle[0] + s_cle[1] + s_cle[2] + s_cle[3];
        p.w = s_cva[0] + s_cva[1] + s_cva[2] + s_cva[3];
        partials[blockIdx.x] = p;   // fire-and-forget, distinct lines
    }
}

__global__ __launch_bounds__(1024) void reduce_finalize_kernel(
        Ws* __restrict__ ws, const uint4* __restrict__ partials,
        int nblocks, float* __restrict__ out) {
    double       sle = 0.0, sva = 0.0;
    unsigned int cle = 0u,  cva = 0u;
    for (int i = threadIdx.x; i < nblocks; i += 1024) {
        const uint4 p = partials[i];
        sle += (double)__uint_as_float(p.x);
        sva += (double)__uint_as_float(p.y);
        cle += p.z;
        cva += p.w;
    }
    __shared__ double       d_le[16], d_va[16];
    __shared__ unsigned int u_le[16], u_va[16];
    const int wid = threadIdx.x >> 6, lane = threadIdx.x & 63;
    const double       r_sle = wave_reduce_d(sle);
    const double       r_sva = wave_reduce_d(sva);
    const unsigned int r_cle = wave_reduce_u(cle);
    const unsigned int r_cva = wave_reduce_u(cva);
    if (lane == 0) { d_le[wid] = r_sle; d_va[wid] = r_sva; u_le[wid] = r_cle; u_va[wid] = r_cva; }
    __syncthreads();
    if (threadIdx.x == 0) {
        double       t_sle = 0.0, t_sva = 0.0;
        unsigned int t_cle = 0u,  t_cva = 0u;
        #pragma unroll
        for (int i = 0; i < 16; ++i) {
            t_sle += d_le[i]; t_sva += d_va[i]; t_cle += u_le[i]; t_cva += u_va[i];
        }
        const unsigned int nv = t_cva;
        const unsigned int k  = nv < MIN_KEPT ? nv : MIN_KEPT;
        if (MIN_KEPT >= nv) {                 // keep all valid
            out[0] = (float)(t_sva / (double)(nv > 0u ? nv : 1u));
            ws->flag = 0u;
        } else if (t_cle >= k) {              // threshold = 0.9 (normal path)
            out[0] = (float)(t_sle / (double)(t_cle > 0u ? t_cle : 1u));
            ws->flag = 0u;
        } else {
            unsigned int cum = t_cle;         // kth prob in (0.9, 1]
            int b = NBINS - 1;
            for (int i = 0; i < NBINS; ++i) {
                cum += ws->hist[i];
                if (cum >= k) { b = i; break; }
            }
            ws->threshold = 0.9f + (float)(b + 1) * (0.1f / (float)NBINS);
            ws->flag = 1u;
            out[0] = 0.0f;                    // overwritten by fallback
        }
    }
}

// Rare path: full recompute with histogram-derived (conservative) threshold;
// finalize fused via last-block arrival counter.
__global__ __launch_bounds__(256) void fallback_kernel(
        const float* __restrict__ pred, const int* __restrict__ tgt,
        Ws* __restrict__ ws, float* __restrict__ out, int npix_q) {
    if (ws->flag == 0u) return;   // normal case: exit immediately
    const float th = ws->threshold;
    const int stride = gridDim.x * blockDim.x;

    float        my_s = 0.0f;
    unsigned int my_c = 0u;
    for (int t = blockIdx.x * blockDim.x + threadIdx.x; t < npix_q; t += stride) {
        const int p0 = t << 2;
        const float* base = pred +
            (((size_t)(p0 >> PIX_SHIFT) * C) << PIX_SHIFT) + (p0 & PIX_MASK);
        const int4 li = *(const int4*)(tgt + p0);
        const int lab[4] = {li.x, li.y, li.z, li.w};
        float s[4] = {0,0,0,0}, l_lab[4] = {0,0,0,0};
        #pragma unroll
        for (int ci = 0; ci < C; ++ci) {
            const float4 v = *(const float4*)(base + ((size_t)ci << PIX_SHIFT));
            const float vv[4] = {v.x, v.y, v.z, v.w};
            #pragma unroll
            for (int j = 0; j < 4; ++j) {
                s[j] += __expf(vv[j]);
                if (lab[j] == ci) l_lab[j] = vv[j];
            }
        }
        #pragma unroll
        for (int j = 0; j < 4; ++j) {
            const float ls   = __logf(s[j]);
            const float nll  = ls - l_lab[j];
            const float prob = __expf(l_lab[j] - ls);
            if (lab[j] != IGNORE_LABEL && prob <= th) { my_c += 1u; my_s += nll; }
        }
    }
    __shared__ float        s_s[4];
    __shared__ unsigned int s_c[4];
    const int wid = threadIdx.x >> 6, lane = threadIdx.x & 63;
    const float        r_s = wave_reduce_f(my_s);
    const unsigned int r_c = wave_reduce_u(my_c);
    if (lane == 0) { s_s[wid] = r_s; s_c[wid] = r_c; }
    __syncthreads();
    if (threadIdx.x == 0) {
        const float        t_s = s_s[0] + s_s[1] + s_s[2] + s_s[3];
        const unsigned int t_c = s_c[0] + s_c[1] + s_c[2] + s_c[3];
        if (t_s != 0.0f) atomicAdd(&ws->sum_p3, (double)t_s);
        if (t_c)         atomicAdd(&ws->cnt_p3, t_c);
        __threadfence();
        const unsigned int prev = atomicAdd(&ws->done2, 1u);
        if (prev == gridDim.x - 1u) {          // last block finalizes
            const unsigned int cnt = ws->cnt_p3;
            out[0] = (float)(ws->sum_p3 / (double)(cnt > 0u ? cnt : 1u));
        }
    }
}

extern "C" void kernel_launch(void* const* d_in, const int* in_sizes, int n_in,
                              void* d_out, int out_size, void* d_ws, size_t ws_size,
                              hipStream_t stream) {
    const float* pred = (const float*)d_in[0];
    const int*   tgt  = (const int*)d_in[1];
    float*       out  = (float*)d_out;
    Ws*          ws   = (Ws*)d_ws;
    uint4*       partials = (uint4*)((char*)d_ws + sizeof(Ws));

    const int npix   = in_sizes[1];            // 2,097,152
    const int npix_q = npix >> 2;
    const int blocks = npix / TILE;            // 2048 tiles

    hipMemsetAsync(d_ws, 0, sizeof(Ws), stream);
    main_pass_kernel<<<blocks, 256, 0, stream>>>(pred, tgt, ws, partials);
    reduce_finalize_kernel<<<1, 1024, 0, stream>>>(ws, partials, blocks, out);
    fallback_kernel<<<128, 256, 0, stream>>>(pred, tgt, ws, out, npix_q);
}